// Round 2
// baseline (824.075 us; speedup 1.0000x reference)
//
#include <hip/hip_runtime.h>

#define DF 128

// ---- deg[row[e]] += w[e]; count[col[e]] += 1 ----
__global__ void degcount_kernel(const int* __restrict__ row, const int* __restrict__ col,
                                const float* __restrict__ w,
                                float* __restrict__ deg, int* __restrict__ count, int E) {
    int e = blockIdx.x * blockDim.x + threadIdx.x;
    if (e < E) {
        atomicAdd(&deg[row[e]], w[e]);
        atomicAdd(&count[col[e]], 1);
    }
}

// ---- exclusive prefix sum of count[0..N) -> off[0..N], single block ----
__global__ __launch_bounds__(1024) void scan_kernel(const int* __restrict__ count,
                                                    int* __restrict__ off, int N) {
    __shared__ int sums[1024];
    const int t = threadIdx.x;
    const int chunk = (N + 1023) / 1024;
    const int base = t * chunk;
    int s = 0;
    for (int i = 0; i < chunk; ++i) {
        int idx = base + i;
        if (idx < N) s += count[idx];
    }
    sums[t] = s;
    __syncthreads();
    for (int d = 1; d < 1024; d <<= 1) {
        int v = (t >= d) ? sums[t - d] : 0;
        __syncthreads();
        sums[t] += v;
        __syncthreads();
    }
    int excl = (t == 0) ? 0 : sums[t - 1];
    for (int i = 0; i < chunk; ++i) {
        int idx = base + i;
        if (idx < N) {
            off[idx] = excl;
            excl += count[idx];
        }
    }
    if (t == 1023) off[N] = excl;   // == E
}

// ---- fill CSR: for each edge, norm + slot in destination bucket ----
__global__ void fill_kernel(const int* __restrict__ row, const int* __restrict__ col,
                            const float* __restrict__ w, const float* __restrict__ deg,
                            int* __restrict__ cursor,
                            int* __restrict__ csr_src, float* __restrict__ csr_w, int E) {
    int e = blockIdx.x * blockDim.x + threadIdx.x;
    if (e < E) {
        int r = row[e], c = col[e];
        float nrm = rsqrtf(deg[r]) * w[e] * rsqrtf(deg[c]);
        int pos = atomicAdd(&cursor[c], 1);
        csr_src[pos] = r;
        csr_w[pos]   = nrm;
    }
}

// ---- H = X @ W^T + b : W row in 128 VGPRs, x-row loads are wave-uniform ----
#define GRPB 64   // rows per block
__global__ __launch_bounds__(256) void gemm_kernel(
    const float* __restrict__ X, const float* __restrict__ W,
    const float* __restrict__ b, float* __restrict__ H, int nrows)
{
    const int t    = threadIdx.x & 127;   // output column
    const int half = threadIdx.x >> 7;    // 0/1: which row stream
    float wreg[DF];
    const float4* wr = (const float4*)(W + t * DF);
#pragma unroll
    for (int j = 0; j < DF / 4; ++j) {
        float4 v = wr[j];
        wreg[4 * j + 0] = v.x; wreg[4 * j + 1] = v.y;
        wreg[4 * j + 2] = v.z; wreg[4 * j + 3] = v.w;
    }
    const float bias = b[t];
    const int nend = min(blockIdx.x * GRPB + GRPB, nrows);
    for (int n = blockIdx.x * GRPB + half; n < nend; n += 2) {
        const float4* xr = (const float4*)(X + (size_t)n * DF);
        float acc = bias;
#pragma unroll
        for (int j = 0; j < DF / 4; ++j) {
            float4 x4 = xr[j];            // same addr across 64 lanes -> 1 L1 txn
            acc = fmaf(x4.x, wreg[4 * j + 0], acc);
            acc = fmaf(x4.y, wreg[4 * j + 1], acc);
            acc = fmaf(x4.z, wreg[4 * j + 2], acc);
            acc = fmaf(x4.w, wreg[4 * j + 3], acc);
        }
        H[(size_t)n * DF + t] = acc;
    }
}

// ---- pull aggregation: out[c] = sum over incoming edges norm * H[src] ----
// 32 lanes per node, float4 per lane. Optional fused ReLU on output.
template <bool RELU_OUT>
__global__ void agg_kernel(const float4* __restrict__ H4,
                           const int* __restrict__ off, const int* __restrict__ src,
                           const float* __restrict__ wgt,
                           float4* __restrict__ O4, int N)
{
    const int gid  = blockIdx.x * blockDim.x + threadIdx.x;
    const int node = gid >> 5;
    const int t    = gid & 31;
    if (node >= N) return;
    const int beg = off[node], end = off[node + 1];
    float4 acc = make_float4(0.f, 0.f, 0.f, 0.f);
    for (int i = beg; i < end; ++i) {
        const int   s = src[i];
        const float w = wgt[i];
        float4 h = H4[(size_t)s * 32 + t];
        acc.x = fmaf(w, h.x, acc.x);
        acc.y = fmaf(w, h.y, acc.y);
        acc.z = fmaf(w, h.z, acc.z);
        acc.w = fmaf(w, h.w, acc.w);
    }
    if (RELU_OUT) {
        acc.x = fmaxf(acc.x, 0.f); acc.y = fmaxf(acc.y, 0.f);
        acc.z = fmaxf(acc.z, 0.f); acc.w = fmaxf(acc.w, 0.f);
    }
    O4[(size_t)node * 32 + t] = acc;
}

extern "C" void kernel_launch(void* const* d_in, const int* in_sizes, int n_in,
                              void* d_out, int out_size, void* d_ws, size_t ws_size,
                              hipStream_t stream) {
    const float* x  = (const float*)d_in[0];
    const int*   ei = (const int*)d_in[1];
    const float* ew = (const float*)d_in[2];
    const float* W1 = (const float*)d_in[3];
    const float* b1 = (const float*)d_in[4];
    const float* W2 = (const float*)d_in[5];
    const float* b2 = (const float*)d_in[6];
    float* out = (float*)d_out;

    const int E = in_sizes[2];        // 600000
    const int N = in_sizes[0] / DF;   // 50000
    const int* row = ei;
    const int* col = ei + E;

    char* ws = (char*)d_ws;
    size_t offb = 0;
    auto alloc = [&](size_t bytes) { char* p = ws + offb; offb = (offb + bytes + 511) & ~(size_t)511; return p; };
    float* deg     = (float*)alloc((size_t)N * 4);
    int*   count   = (int*)alloc((size_t)N * 4);
    int*   csr_off = (int*)alloc((size_t)(N + 1) * 4);
    int*   cursor  = (int*)alloc((size_t)N * 4);
    int*   csr_src = (int*)alloc((size_t)E * 4);
    float* csr_w   = (float*)alloc((size_t)E * 4);
    float* h1      = (float*)alloc((size_t)N * DF * 4);  // linear out (reused both layers)
    float* agg1    = (float*)alloc((size_t)N * DF * 4);  // relu(aggregate) of layer 1
    (void)ws_size;

    hipMemsetAsync(deg,   0, (size_t)N * 4, stream);
    hipMemsetAsync(count, 0, (size_t)N * 4, stream);

    const int TB = 256;
    const int eblocks = (E + TB - 1) / TB;

    // ---- build normalization + CSR (by destination) ----
    degcount_kernel<<<eblocks, TB, 0, stream>>>(row, col, ew, deg, count, E);
    scan_kernel<<<1, 1024, 0, stream>>>(count, csr_off, N);
    hipMemcpyAsync(cursor, csr_off, (size_t)N * 4, hipMemcpyDeviceToDevice, stream);
    fill_kernel<<<eblocks, TB, 0, stream>>>(row, col, ew, deg, cursor, csr_src, csr_w, E);

    // ---- layer 1 ----
    const int gemm_blocks = (N + GRPB - 1) / GRPB;
    gemm_kernel<<<gemm_blocks, 256, 0, stream>>>(x, W1, b1, h1, N);
    const int agg_threads = N * 32;
    const int agg_blocks = (agg_threads + TB - 1) / TB;
    agg_kernel<true><<<agg_blocks, TB, 0, stream>>>((const float4*)h1, csr_off, csr_src, csr_w,
                                                    (float4*)agg1, N);
    // ---- layer 2 ----
    gemm_kernel<<<gemm_blocks, 256, 0, stream>>>(agg1, W2, b2, h1, N);
    agg_kernel<false><<<agg_blocks, TB, 0, stream>>>((const float4*)h1, csr_off, csr_src, csr_w,
                                                     (float4*)out, N);
}

// Round 3
// 443.510 us; speedup vs baseline: 1.8581x; 1.8581x over previous
//
#include <hip/hip_runtime.h>

#define DF 128

// ---- deg[row[e]] += w[e]; count[col[e]] += 1 ----
__global__ void degcount_kernel(const int* __restrict__ row, const int* __restrict__ col,
                                const float* __restrict__ w,
                                float* __restrict__ deg, int* __restrict__ count, int E) {
    int e = blockIdx.x * blockDim.x + threadIdx.x;
    if (e < E) {
        atomicAdd(&deg[row[e]], w[e]);
        atomicAdd(&count[col[e]], 1);
    }
}

// ---- exclusive prefix sum of count[0..N) -> off[0..N], single block ----
__global__ __launch_bounds__(1024) void scan_kernel(const int* __restrict__ count,
                                                    int* __restrict__ off, int N) {
    __shared__ int sums[1024];
    const int t = threadIdx.x;
    const int chunk = (N + 1023) / 1024;
    const int base = t * chunk;
    int s = 0;
    for (int i = 0; i < chunk; ++i) {
        int idx = base + i;
        if (idx < N) s += count[idx];
    }
    sums[t] = s;
    __syncthreads();
    for (int d = 1; d < 1024; d <<= 1) {
        int v = (t >= d) ? sums[t - d] : 0;
        __syncthreads();
        sums[t] += v;
        __syncthreads();
    }
    int excl = (t == 0) ? 0 : sums[t - 1];
    for (int i = 0; i < chunk; ++i) {
        int idx = base + i;
        if (idx < N) {
            off[idx] = excl;
            excl += count[idx];
        }
    }
    if (t == 1023) off[N] = excl;   // == E
}

// ---- fill CSR: for each edge, norm + slot in destination bucket ----
__global__ void fill_kernel(const int* __restrict__ row, const int* __restrict__ col,
                            const float* __restrict__ w, const float* __restrict__ deg,
                            int* __restrict__ cursor,
                            int* __restrict__ csr_src, float* __restrict__ csr_w, int E) {
    int e = blockIdx.x * blockDim.x + threadIdx.x;
    if (e < E) {
        int r = row[e], c = col[e];
        float nrm = rsqrtf(deg[r]) * w[e] * rsqrtf(deg[c]);
        int pos = atomicAdd(&cursor[c], 1);
        csr_src[pos] = r;
        csr_w[pos]   = nrm;
    }
}

// ---- H = X @ W^T + b : register-blocked tile GEMM ----
// block: 256 thr, tile 64 rows x 128 cols; thread: 8 rows x 4 cols (32 indep accs).
// X tile 32KB LDS staged once; W staged k-major in 32-k chunks (16KB).
#define TROWS 64
__global__ __launch_bounds__(256) void gemm_kernel(
    const float* __restrict__ X, const float* __restrict__ W,
    const float* __restrict__ b, float* __restrict__ H, int nrows)
{
    __shared__ float Xs[TROWS * DF];   // [64][128]
    __shared__ float Wsk[32 * DF];     // k-major chunk [32 k][128 col]

    const int tid  = threadIdx.x;
    const int rgrp = tid >> 5;         // 0..7 -> rows rgrp*8 .. +7
    const int cgrp = tid & 31;         // cols cgrp*4 .. +3
    const int n0   = blockIdx.x * TROWS;

    // stage X tile, coalesced float4 (2048 float4 = 256 thr x 8)
#pragma unroll
    for (int i = 0; i < 8; ++i) {
        int idx = tid + i * 256;       // 0..2047
        int r   = idx >> 5;
        int kk  = idx & 31;
        int n   = n0 + r;
        float4 v = make_float4(0.f, 0.f, 0.f, 0.f);
        if (n < nrows) v = ((const float4*)(X + (size_t)n * DF))[kk];
        ((float4*)Xs)[idx] = v;
    }

    float4 acc[8];
    const float4 bias = ((const float4*)b)[cgrp];
#pragma unroll
    for (int r = 0; r < 8; ++r) acc[r] = bias;

    const float4* Xs4 = (const float4*)Xs;
    const float4* Ws4 = (const float4*)Wsk;

    for (int k0 = 0; k0 < DF; k0 += 32) {
        __syncthreads();               // prev-chunk readers done (also covers Xs staging)
        // stage W chunk transposed: Wsk[k][c] = W[c][k0+k]; coalesced global b128 reads
        // 128 cols x 8 float4 = 1024; 256 thr x 4
#pragma unroll
        for (int i = 0; i < 4; ++i) {
            int idx = tid + i * 256;   // 0..1023
            int c   = idx >> 3;        // 0..127
            int kk  = idx & 7;         // float4 along k
            float4 v = ((const float4*)(W + (size_t)c * DF + k0))[kk];
            int kb = kk * 4;
            Wsk[(kb + 0) * DF + c] = v.x;
            Wsk[(kb + 1) * DF + c] = v.y;
            Wsk[(kb + 2) * DF + c] = v.z;
            Wsk[(kb + 3) * DF + c] = v.w;
        }
        __syncthreads();

#pragma unroll
        for (int kk = 0; kk < 8; ++kk) {               // 4 k's per step
            const int kb = (k0 >> 2) + kk;
            float4 w0 = Ws4[(kk * 4 + 0) * 32 + cgrp]; // contiguous b128, conflict-free
            float4 w1 = Ws4[(kk * 4 + 1) * 32 + cgrp];
            float4 w2 = Ws4[(kk * 4 + 2) * 32 + cgrp];
            float4 w3 = Ws4[(kk * 4 + 3) * 32 + cgrp];
#pragma unroll
            for (int r = 0; r < 8; ++r) {
                float4 x4 = Xs4[(rgrp * 8 + r) * 32 + kb];   // half-wave broadcast
                acc[r].x = fmaf(x4.x, w0.x, acc[r].x);
                acc[r].y = fmaf(x4.x, w0.y, acc[r].y);
                acc[r].z = fmaf(x4.x, w0.z, acc[r].z);
                acc[r].w = fmaf(x4.x, w0.w, acc[r].w);
                acc[r].x = fmaf(x4.y, w1.x, acc[r].x);
                acc[r].y = fmaf(x4.y, w1.y, acc[r].y);
                acc[r].z = fmaf(x4.y, w1.z, acc[r].z);
                acc[r].w = fmaf(x4.y, w1.w, acc[r].w);
                acc[r].x = fmaf(x4.z, w2.x, acc[r].x);
                acc[r].y = fmaf(x4.z, w2.y, acc[r].y);
                acc[r].z = fmaf(x4.z, w2.z, acc[r].z);
                acc[r].w = fmaf(x4.z, w2.w, acc[r].w);
                acc[r].x = fmaf(x4.w, w3.x, acc[r].x);
                acc[r].y = fmaf(x4.w, w3.y, acc[r].y);
                acc[r].z = fmaf(x4.w, w3.z, acc[r].z);
                acc[r].w = fmaf(x4.w, w3.w, acc[r].w);
            }
        }
    }

#pragma unroll
    for (int r = 0; r < 8; ++r) {
        int n = n0 + rgrp * 8 + r;
        if (n < nrows) ((float4*)(H + (size_t)n * DF))[cgrp] = acc[r];  // coalesced b128
    }
}

// ---- pull aggregation: out[c] = sum over incoming edges norm * H[src] ----
template <bool RELU_OUT>
__global__ void agg_kernel(const float4* __restrict__ H4,
                           const int* __restrict__ off, const int* __restrict__ src,
                           const float* __restrict__ wgt,
                           float4* __restrict__ O4, int N)
{
    const int gid  = blockIdx.x * blockDim.x + threadIdx.x;
    const int node = gid >> 5;
    const int t    = gid & 31;
    if (node >= N) return;
    const int beg = off[node], end = off[node + 1];
    float4 acc = make_float4(0.f, 0.f, 0.f, 0.f);
    for (int i = beg; i < end; ++i) {
        const int   s = src[i];
        const float w = wgt[i];
        float4 h = H4[(size_t)s * 32 + t];
        acc.x = fmaf(w, h.x, acc.x);
        acc.y = fmaf(w, h.y, acc.y);
        acc.z = fmaf(w, h.z, acc.z);
        acc.w = fmaf(w, h.w, acc.w);
    }
    if (RELU_OUT) {
        acc.x = fmaxf(acc.x, 0.f); acc.y = fmaxf(acc.y, 0.f);
        acc.z = fmaxf(acc.z, 0.f); acc.w = fmaxf(acc.w, 0.f);
    }
    O4[(size_t)node * 32 + t] = acc;
}

extern "C" void kernel_launch(void* const* d_in, const int* in_sizes, int n_in,
                              void* d_out, int out_size, void* d_ws, size_t ws_size,
                              hipStream_t stream) {
    const float* x  = (const float*)d_in[0];
    const int*   ei = (const int*)d_in[1];
    const float* ew = (const float*)d_in[2];
    const float* W1 = (const float*)d_in[3];
    const float* b1 = (const float*)d_in[4];
    const float* W2 = (const float*)d_in[5];
    const float* b2 = (const float*)d_in[6];
    float* out = (float*)d_out;

    const int E = in_sizes[2];        // 600000
    const int N = in_sizes[0] / DF;   // 50000
    const int* row = ei;
    const int* col = ei + E;

    char* ws = (char*)d_ws;
    size_t offb = 0;
    auto alloc = [&](size_t bytes) { char* p = ws + offb; offb = (offb + bytes + 511) & ~(size_t)511; return p; };
    float* deg     = (float*)alloc((size_t)N * 4);
    int*   count   = (int*)alloc((size_t)N * 4);
    int*   csr_off = (int*)alloc((size_t)(N + 1) * 4);
    int*   cursor  = (int*)alloc((size_t)N * 4);
    int*   csr_src = (int*)alloc((size_t)E * 4);
    float* csr_w   = (float*)alloc((size_t)E * 4);
    float* h1      = (float*)alloc((size_t)N * DF * 4);  // linear out (reused both layers)
    float* agg1    = (float*)alloc((size_t)N * DF * 4);  // relu(aggregate) of layer 1
    (void)ws_size;

    hipMemsetAsync(deg,   0, (size_t)N * 4, stream);
    hipMemsetAsync(count, 0, (size_t)N * 4, stream);

    const int TB = 256;
    const int eblocks = (E + TB - 1) / TB;

    // ---- build normalization + CSR (by destination) ----
    degcount_kernel<<<eblocks, TB, 0, stream>>>(row, col, ew, deg, count, E);
    scan_kernel<<<1, 1024, 0, stream>>>(count, csr_off, N);
    hipMemcpyAsync(cursor, csr_off, (size_t)N * 4, hipMemcpyDeviceToDevice, stream);
    fill_kernel<<<eblocks, TB, 0, stream>>>(row, col, ew, deg, cursor, csr_src, csr_w, E);

    // ---- layer 1 ----
    const int gemm_blocks = (N + TROWS - 1) / TROWS;
    gemm_kernel<<<gemm_blocks, 256, 0, stream>>>(x, W1, b1, h1, N);
    const int agg_blocks = (N * 32 + TB - 1) / TB;
    agg_kernel<true><<<agg_blocks, TB, 0, stream>>>((const float4*)h1, csr_off, csr_src, csr_w,
                                                    (float4*)agg1, N);
    // ---- layer 2 ----
    gemm_kernel<<<gemm_blocks, 256, 0, stream>>>(agg1, W2, b2, h1, N);
    agg_kernel<false><<<agg_blocks, TB, 0, stream>>>((const float4*)h1, csr_off, csr_src, csr_w,
                                                     (float4*)out, N);
}

// Round 4
// 355.724 us; speedup vs baseline: 2.3166x; 1.2468x over previous
//
#include <hip/hip_runtime.h>

#define DF 128

// ---- deg[row[e]] += w[e]; count[col[e]] += 1 ----
__global__ void degcount_kernel(const int* __restrict__ row, const int* __restrict__ col,
                                const float* __restrict__ w,
                                float* __restrict__ deg, int* __restrict__ count, int E) {
    int e = blockIdx.x * blockDim.x + threadIdx.x;
    if (e < E) {
        atomicAdd(&deg[row[e]], w[e]);
        atomicAdd(&count[col[e]], 1);
    }
}

// ---- two-level exclusive scan: A) per-block reduce ----
__global__ __launch_bounds__(256) void scanA_kernel(const int* __restrict__ count,
                                                    int* __restrict__ bsum, int N) {
    const int t = threadIdx.x;
    const int i = blockIdx.x * 256 + t;
    int v = (i < N) ? count[i] : 0;
#pragma unroll
    for (int d = 32; d > 0; d >>= 1) v += __shfl_down(v, d, 64);
    __shared__ int ws[4];
    if ((t & 63) == 0) ws[t >> 6] = v;
    __syncthreads();
    if (t == 0) bsum[blockIdx.x] = ws[0] + ws[1] + ws[2] + ws[3];
}

// ---- B) single-block scan of block sums (nb <= 1024) ----
__global__ __launch_bounds__(1024) void scanB_kernel(const int* __restrict__ bsum,
                                                     int* __restrict__ bpref, int nb,
                                                     int* __restrict__ offN, int E) {
    __shared__ int s[1024];
    const int t = threadIdx.x;
    s[t] = (t < nb) ? bsum[t] : 0;
    __syncthreads();
    for (int d = 1; d < 1024; d <<= 1) {
        int v = (t >= d) ? s[t - d] : 0;
        __syncthreads();
        s[t] += v;
        __syncthreads();
    }
    if (t < nb) bpref[t] = (t == 0) ? 0 : s[t - 1];
    if (t == 0) *offN = E;
}

// ---- C) per-block local scan + add block prefix; also writes cursor ----
__global__ __launch_bounds__(256) void scanC_kernel(const int* __restrict__ count,
                                                    const int* __restrict__ bpref,
                                                    int* __restrict__ off,
                                                    int* __restrict__ cursor, int N) {
    __shared__ int s[256];
    const int t = threadIdx.x;
    const int i = blockIdx.x * 256 + t;
    const int v = (i < N) ? count[i] : 0;
    s[t] = v;
    __syncthreads();
    for (int d = 1; d < 256; d <<= 1) {
        int u = (t >= d) ? s[t - d] : 0;
        __syncthreads();
        s[t] += u;
        __syncthreads();
    }
    const int excl = bpref[blockIdx.x] + s[t] - v;
    if (i < N) {
        off[i] = excl;
        cursor[i] = excl;
    }
}

// ---- fill CSR: for each edge, norm + slot in destination bucket ----
__global__ void fill_kernel(const int* __restrict__ row, const int* __restrict__ col,
                            const float* __restrict__ w, const float* __restrict__ deg,
                            int* __restrict__ cursor,
                            int* __restrict__ csr_src, float* __restrict__ csr_w, int E) {
    int e = blockIdx.x * blockDim.x + threadIdx.x;
    if (e < E) {
        int r = row[e], c = col[e];
        float nrm = rsqrtf(deg[r]) * w[e] * rsqrtf(deg[c]);
        int pos = atomicAdd(&cursor[c], 1);
        csr_src[pos] = r;
        csr_w[pos]   = nrm;
    }
}

// ---- H = X @ W^T + b : register-blocked tile GEMM ----
// block: 256 thr, tile 64 rows x 128 cols; thread: 8 rows x 4 cols (32 indep accs).
#define TROWS 64
__global__ __launch_bounds__(256) void gemm_kernel(
    const float* __restrict__ X, const float* __restrict__ W,
    const float* __restrict__ b, float* __restrict__ H, int nrows)
{
    __shared__ float Xs[TROWS * DF];   // [64][128]
    __shared__ float Wsk[32 * DF];     // k-major chunk [32 k][128 col]

    const int tid  = threadIdx.x;
    const int rgrp = tid >> 5;         // 0..7 -> rows rgrp*8 .. +7
    const int cgrp = tid & 31;         // cols cgrp*4 .. +3
    const int n0   = blockIdx.x * TROWS;

#pragma unroll
    for (int i = 0; i < 8; ++i) {
        int idx = tid + i * 256;       // 0..2047
        int r   = idx >> 5;
        int kk  = idx & 31;
        int n   = n0 + r;
        float4 v = make_float4(0.f, 0.f, 0.f, 0.f);
        if (n < nrows) v = ((const float4*)(X + (size_t)n * DF))[kk];
        ((float4*)Xs)[idx] = v;
    }

    float4 acc[8];
    const float4 bias = ((const float4*)b)[cgrp];
#pragma unroll
    for (int r = 0; r < 8; ++r) acc[r] = bias;

    const float4* Xs4 = (const float4*)Xs;
    const float4* Ws4 = (const float4*)Wsk;

    for (int k0 = 0; k0 < DF; k0 += 32) {
        __syncthreads();
#pragma unroll
        for (int i = 0; i < 4; ++i) {
            int idx = tid + i * 256;   // 0..1023
            int c   = idx >> 3;        // 0..127
            int kk  = idx & 7;
            float4 v = ((const float4*)(W + (size_t)c * DF + k0))[kk];
            int kb = kk * 4;
            Wsk[(kb + 0) * DF + c] = v.x;
            Wsk[(kb + 1) * DF + c] = v.y;
            Wsk[(kb + 2) * DF + c] = v.z;
            Wsk[(kb + 3) * DF + c] = v.w;
        }
        __syncthreads();

#pragma unroll
        for (int kk = 0; kk < 8; ++kk) {
            const int kb = (k0 >> 2) + kk;
            float4 w0 = Ws4[(kk * 4 + 0) * 32 + cgrp];
            float4 w1 = Ws4[(kk * 4 + 1) * 32 + cgrp];
            float4 w2 = Ws4[(kk * 4 + 2) * 32 + cgrp];
            float4 w3 = Ws4[(kk * 4 + 3) * 32 + cgrp];
#pragma unroll
            for (int r = 0; r < 8; ++r) {
                float4 x4 = Xs4[(rgrp * 8 + r) * 32 + kb];
                acc[r].x = fmaf(x4.x, w0.x, acc[r].x);
                acc[r].y = fmaf(x4.x, w0.y, acc[r].y);
                acc[r].z = fmaf(x4.x, w0.z, acc[r].z);
                acc[r].w = fmaf(x4.x, w0.w, acc[r].w);
                acc[r].x = fmaf(x4.y, w1.x, acc[r].x);
                acc[r].y = fmaf(x4.y, w1.y, acc[r].y);
                acc[r].z = fmaf(x4.y, w1.z, acc[r].z);
                acc[r].w = fmaf(x4.y, w1.w, acc[r].w);
                acc[r].x = fmaf(x4.z, w2.x, acc[r].x);
                acc[r].y = fmaf(x4.z, w2.y, acc[r].y);
                acc[r].z = fmaf(x4.z, w2.z, acc[r].z);
                acc[r].w = fmaf(x4.z, w2.w, acc[r].w);
                acc[r].x = fmaf(x4.w, w3.x, acc[r].x);
                acc[r].y = fmaf(x4.w, w3.y, acc[r].y);
                acc[r].z = fmaf(x4.w, w3.z, acc[r].z);
                acc[r].w = fmaf(x4.w, w3.w, acc[r].w);
            }
        }
    }

#pragma unroll
    for (int r = 0; r < 8; ++r) {
        int n = n0 + rgrp * 8 + r;
        if (n < nrows) ((float4*)(H + (size_t)n * DF))[cgrp] = acc[r];
    }
}

// ---- pull aggregation: out[c] = sum over incoming edges norm * H[src] ----
template <bool RELU_OUT>
__global__ void agg_kernel(const float4* __restrict__ H4,
                           const int* __restrict__ off, const int* __restrict__ src,
                           const float* __restrict__ wgt,
                           float4* __restrict__ O4, int N)
{
    const int gid  = blockIdx.x * blockDim.x + threadIdx.x;
    const int node = gid >> 5;
    const int t    = gid & 31;
    if (node >= N) return;
    const int beg = off[node], end = off[node + 1];
    float4 acc = make_float4(0.f, 0.f, 0.f, 0.f);
    for (int i = beg; i < end; ++i) {
        const int   s = src[i];
        const float w = wgt[i];
        float4 h = H4[(size_t)s * 32 + t];
        acc.x = fmaf(w, h.x, acc.x);
        acc.y = fmaf(w, h.y, acc.y);
        acc.z = fmaf(w, h.z, acc.z);
        acc.w = fmaf(w, h.w, acc.w);
    }
    if (RELU_OUT) {
        acc.x = fmaxf(acc.x, 0.f); acc.y = fmaxf(acc.y, 0.f);
        acc.z = fmaxf(acc.z, 0.f); acc.w = fmaxf(acc.w, 0.f);
    }
    O4[(size_t)node * 32 + t] = acc;
}

extern "C" void kernel_launch(void* const* d_in, const int* in_sizes, int n_in,
                              void* d_out, int out_size, void* d_ws, size_t ws_size,
                              hipStream_t stream) {
    const float* x  = (const float*)d_in[0];
    const int*   ei = (const int*)d_in[1];
    const float* ew = (const float*)d_in[2];
    const float* W1 = (const float*)d_in[3];
    const float* b1 = (const float*)d_in[4];
    const float* W2 = (const float*)d_in[5];
    const float* b2 = (const float*)d_in[6];
    float* out = (float*)d_out;

    const int E = in_sizes[2];        // 600000
    const int N = in_sizes[0] / DF;   // 50000
    const int* row = ei;
    const int* col = ei + E;

    char* ws = (char*)d_ws;
    size_t offb = 0;
    auto alloc = [&](size_t bytes) { char* p = ws + offb; offb = (offb + bytes + 511) & ~(size_t)511; return p; };
    float* deg     = (float*)alloc((size_t)N * 4);
    int*   count   = (int*)alloc((size_t)N * 4);
    int*   csr_off = (int*)alloc((size_t)(N + 1) * 4);
    int*   cursor  = (int*)alloc((size_t)N * 4);
    int*   bsum    = (int*)alloc((size_t)1024 * 4);
    int*   bpref   = (int*)alloc((size_t)1024 * 4);
    int*   csr_src = (int*)alloc((size_t)E * 4);
    float* csr_w   = (float*)alloc((size_t)E * 4);
    float* h1      = (float*)alloc((size_t)N * DF * 4);  // linear out (reused both layers)
    float* agg1    = (float*)alloc((size_t)N * DF * 4);  // relu(aggregate) of layer 1
    (void)ws_size;

    hipMemsetAsync(deg,   0, (size_t)N * 4, stream);
    hipMemsetAsync(count, 0, (size_t)N * 4, stream);

    const int TB = 256;
    const int eblocks = (E + TB - 1) / TB;
    const int nb = (N + 255) / 256;   // 196 <= 1024

    // ---- build normalization + CSR (by destination) ----
    degcount_kernel<<<eblocks, TB, 0, stream>>>(row, col, ew, deg, count, E);
    scanA_kernel<<<nb, 256, 0, stream>>>(count, bsum, N);
    scanB_kernel<<<1, 1024, 0, stream>>>(bsum, bpref, nb, csr_off + N, E);
    scanC_kernel<<<nb, 256, 0, stream>>>(count, bpref, csr_off, cursor, N);
    fill_kernel<<<eblocks, TB, 0, stream>>>(row, col, ew, deg, cursor, csr_src, csr_w, E);

    // ---- layer 1 ----
    const int gemm_blocks = (N + TROWS - 1) / TROWS;
    gemm_kernel<<<gemm_blocks, 256, 0, stream>>>(x, W1, b1, h1, N);
    const int agg_blocks = (N * 32 + TB - 1) / TB;
    agg_kernel<true><<<agg_blocks, TB, 0, stream>>>((const float4*)h1, csr_off, csr_src, csr_w,
                                                    (float4*)agg1, N);
    // ---- layer 2 ----
    gemm_kernel<<<gemm_blocks, 256, 0, stream>>>(agg1, W2, b2, h1, N);
    agg_kernel<false><<<agg_blocks, TB, 0, stream>>>((const float4*)h1, csr_off, csr_src, csr_w,
                                                     (float4*)out, N);
}